// Round 10
// baseline (148.683 us; speedup 1.0000x reference)
//
#include <hip/hip_runtime.h>

#define LOG2E 1.44269504088896340736f

typedef _Float16 f16_t;
typedef f16_t f16x2 __attribute__((ext_vector_type(2)));
typedef f16_t f16x4 __attribute__((ext_vector_type(4)));
typedef f16_t f16x8 __attribute__((ext_vector_type(8)));
typedef float f32x4 __attribute__((ext_vector_type(4)));

// Problem constants: N=4096 nodes, F_in=512, F_out=128, H=8 heads.

// ---- K0a: pack adjacency (int32 0/1, 64MB) into bitmask (2MB) ----
__global__ __launch_bounds__(256) void k_pack_adj(const int* __restrict__ adj,
                                                  unsigned char* __restrict__ mask8) {
  const int t = blockIdx.x * 256 + threadIdx.x;  // 2M threads
  const int4 a = ((const int4*)adj)[t * 2];
  const int4 b = ((const int4*)adj)[t * 2 + 1];
  unsigned v = (a.x > 0) | ((a.y > 0) << 1) | ((a.z > 0) << 2) | ((a.w > 0) << 3) |
               ((b.x > 0) << 4) | ((b.y > 0) << 5) | ((b.z > 0) << 6) | ((b.w > 0) << 7);
  mask8[t] = (unsigned char)v;
}

// ---- K0b: x fp32 -> fp16 ----
__global__ __launch_bounds__(256) void k_cvt_x(const float* __restrict__ x,
                                               f16_t* __restrict__ xh) {
  const int t = blockIdx.x * 256 + threadIdx.x;
  const f32x4 a = ((const f32x4*)x)[t * 2];
  const f32x4 b = ((const f32x4*)x)[t * 2 + 1];
  f16x8 o;
#pragma unroll
  for (int i = 0; i < 4; ++i) { o[i] = (f16_t)a[i]; o[i + 4] = (f16_t)b[i]; }
  ((f16x8*)xh)[t] = o;
}

// ---- K0c: W [h][k][o] fp32 -> WT [h][o][k] fp16 ----
__global__ __launch_bounds__(256) void k_cvt_w(const float* __restrict__ W,
                                               f16_t* __restrict__ WT) {
  const int t = blockIdx.x * 256 + threadIdx.x;  // 524288
  const int k = t & 511, o = (t >> 9) & 127, h = t >> 16;
  WT[t] = (f16_t)W[((h << 9) + k) * 128 + o];
}

// ---- K1: Wh = x@W per head (fp16 MFMA). Store WhB pre-swizzled in PV
// B-fragment order; epilogue computes piecewise-exp tables
// EA=2^(fs*L), EA2=2^(0.2*fs*L), EB=2^(fd*L), EB2=2^(0.2*fd*L) as fp16.
__global__ __launch_bounds__(256) void k_gemm_wh(const f16_t* __restrict__ xh,
                                                 const f16_t* __restrict__ WT,
                                                 const float* __restrict__ a_src,
                                                 const float* __restrict__ a_dst,
                                                 f16_t* __restrict__ WhB,
                                                 f16_t* __restrict__ EA,
                                                 f16_t* __restrict__ EA2,
                                                 f16_t* __restrict__ EB,
                                                 f16_t* __restrict__ EB2) {
  const int h = blockIdx.y;
  const int n0 = blockIdx.x * 64;
  const int lane = threadIdx.x & 63;
  const int w = threadIdx.x >> 6;
  const int col = lane & 15;
  const int kg = lane >> 4;
  const f16_t* xrow = xh + (size_t)(n0 + w * 16 + col) * 512 + kg * 8;
  const f16_t* wb = WT + ((size_t)h << 16) + (size_t)col * 512 + kg * 8;
  f32x4 acc[8] = {};
  for (int kk = 0; kk < 512; kk += 32) {
    const f16x8 a = *(const f16x8*)(xrow + kk);
#pragma unroll
    for (int ot = 0; ot < 8; ++ot) {
      const f16x8 b = *(const f16x8*)(wb + ot * (16 * 512) + kk);
      acc[ot] = __builtin_amdgcn_mfma_f32_16x16x32_f16(a, b, acc[ot], 0, 0, 0);
    }
  }
  float ps[4] = {0.f, 0.f, 0.f, 0.f}, pd[4] = {0.f, 0.f, 0.f, 0.f};
#pragma unroll
  for (int ot = 0; ot < 8; ++ot) {
    const float as = a_src[h * 128 + ot * 16 + col];
    const float ad = a_dst[h * 128 + ot * 16 + col];
#pragma unroll
    for (int r = 0; r < 4; ++r) { ps[r] += acc[ot][r] * as; pd[r] += acc[ot][r] * ad; }
  }
#pragma unroll
  for (int m = 1; m < 16; m <<= 1) {
#pragma unroll
    for (int r = 0; r < 4; ++r) {
      ps[r] += __shfl_xor(ps[r], m, 64);
      pd[r] += __shfl_xor(pd[r], m, 64);
    }
  }
  const int nb = n0 + w * 16 + kg * 4;  // node index of acc[.][0]
  if (col == 0) {
#pragma unroll
    for (int r = 0; r < 4; ++r) {
      const float fs = ps[r] * LOG2E;
      const float fd = pd[r] * LOG2E;
      const int idx = h * 4096 + nb + r;
      EA[idx] = (f16_t)__builtin_amdgcn_exp2f(fs);
      EA2[idx] = (f16_t)__builtin_amdgcn_exp2f(0.2f * fs);
      EB[idx] = (f16_t)__builtin_amdgcn_exp2f(fd);
      EB2[idx] = (f16_t)__builtin_amdgcn_exp2f(0.2f * fd);
    }
  }
  // swizzled store: (h,o,j) -> WhB[((h*128+j/32)*8+o/16)*512 + ((j>>3)&3)*128 + (o&15)*8 + (j&7)]
  const int jb = nb >> 5;
  const int kgt = (nb >> 3) & 3;
  const int e0 = nb & 4;
  const size_t base = ((size_t)(h * 128 + jb) * 8) * 512 + kgt * 128 + col * 8 + e0;
#pragma unroll
  for (int ot = 0; ot < 8; ++ot) {
    f16x4 v;
#pragma unroll
    for (int r = 0; r < 4; ++r) v[r] = (f16_t)acc[ot][r];
    *(f16x4*)(WhB + base + ot * 512) = v;
  }
}

// ---- K2: masked softmax-numerator + PV partials, o-split across waves ----
// Block = 4 waves sharing 64 rows x 1024-j slice; wave w owns o-quarter
// (2 B-frags reused over 4 row-groups). Mask tile (8KB) staged in LDS once
// (pitch 144 -> 2-way-free b128 reads); 16-entry nibble LUTs (conflict-free
// b64). B/EB register-prefetched 1 iter ahead. den fdot2 on wave 0 only.
// grid = 64 i-tiles x 8 heads x S=4 slices = 2048 blocks = 8 blocks/CU
// (8 waves/SIMD at VGPR<=64) -- occupancy is the R9 limiter being fixed.
__global__ __launch_bounds__(256, 4) void k_pv(const f16_t* __restrict__ WhB,
                                               const f16_t* __restrict__ EA,
                                               const f16_t* __restrict__ EA2,
                                               const f16_t* __restrict__ EB,
                                               const f16_t* __restrict__ EB2,
                                               const unsigned char* __restrict__ mask,
                                               f16_t* __restrict__ num_ws,
                                               float* __restrict__ den_ws) {
  __shared__ __align__(16) unsigned char lds_mask[64 * 144];
  __shared__ __align__(16) unsigned short lut4[16][4];
  const int bx = blockIdx.x;
  const int h = bx & 7;                  // head -> XCD round-robin
  const int i0 = ((bx >> 3) & 63) * 64;  // 64-row i-tile
  const int s = bx >> 9;                 // j-slice (0..3)
  const int jbeg = s * 1024;
  // stage mask tile: 64 rows x 128B, one-time coalesced copy (4 thr/row x 32B)
  {
    const int t = threadIdx.x;
    if (t < 16) {
#pragma unroll
      for (int e = 0; e < 4; ++e) lut4[t][e] = ((t >> e) & 1) ? 0x3C00 : 0;
    }
    const int row = t >> 2, ch = (t & 3) * 32;
    const uint4* src = (const uint4*)(mask + (size_t)(i0 + row) * 512 + (jbeg >> 3) + ch);
    uint4* dst = (uint4*)(lds_mask + row * 144 + ch);
    dst[0] = src[0];
    dst[1] = src[1];
  }
  __syncthreads();
  const int lane = threadIdx.x & 63;
  const int w = threadIdx.x >> 6;        // o-quarter
  const int col = lane & 15, kg = lane >> 4;
  const bool w0 = (w == 0);
  const int sh = kg * 8;
  f16x2 As[4], A2s[4];
#pragma unroll
  for (int g = 0; g < 4; ++g) {
    const f16_t a = EA[h * 4096 + i0 + g * 16 + col];
    const f16_t a2 = EA2[h * 4096 + i0 + g * 16 + col];
    As[g] = (f16x2){a, a};
    A2s[g] = (f16x2){a2, a2};
  }
  const f16_t* EBp = EB + h * 4096 + jbeg + kg * 8;
  const f16_t* EB2p = EB2 + h * 4096 + jbeg + kg * 8;
  const f16_t* whB = WhB + ((size_t)h << 19) + (size_t)(jbeg >> 5) * 4096 + (2 * w) * 512 + lane * 8;
  f32x4 acc[4][2] = {};
  float den_s[4] = {0.f, 0.f, 0.f, 0.f};
  const f16x2 ones2 = {(f16_t)1.0f, (f16_t)1.0f};
  // prefetch iter 0
  f16x8 cb0 = *(const f16x8*)(whB);
  f16x8 cb1 = *(const f16x8*)(whB + 512);
  f16x8 cvb = *(const f16x8*)(EBp);
  f16x8 cvb2 = *(const f16x8*)(EB2p);
  for (int it4 = 0; it4 < 8; ++it4) {
    uint4 md[4];
#pragma unroll
    for (int g = 0; g < 4; ++g) {
      md[g] = *(const uint4*)(lds_mask + (g * 16 + col) * 144 + it4 * 16);
    }
#pragma unroll
    for (int q = 0; q < 4; ++q) {
      const int itn = (it4 * 4 + q + 1) & 31;
      const f16_t* wpn = whB + (size_t)itn * 4096;
      const f16x8 nb0 = *(const f16x8*)(wpn);
      const f16x8 nb1 = *(const f16x8*)(wpn + 512);
      const f16x8 nvb = *(const f16x8*)(EBp + itn * 32);
      const f16x8 nvb2 = *(const f16x8*)(EB2p + itn * 32);
      const f16x2* vbp = (const f16x2*)&cvb;
      const f16x2* vb2p = (const f16x2*)&cvb2;
      f16x8 ag[4];
#pragma unroll
      for (int g = 0; g < 4; ++g) {
        const unsigned mw = (q == 0) ? md[g].x : (q == 1) ? md[g].y : (q == 2) ? md[g].z : md[g].w;
        const unsigned bb = (mw >> sh) & 255u;
        const f16x4 lmL = *(const f16x4*)(&lut4[bb & 15u][0]);
        const f16x4 lmH = *(const f16x4*)(&lut4[bb >> 4][0]);
        const f16x2 p0 = __builtin_elementwise_max(As[g] * vbp[0], A2s[g] * vb2p[0]) * ((const f16x2*)&lmL)[0];
        const f16x2 p1 = __builtin_elementwise_max(As[g] * vbp[1], A2s[g] * vb2p[1]) * ((const f16x2*)&lmL)[1];
        const f16x2 p2 = __builtin_elementwise_max(As[g] * vbp[2], A2s[g] * vb2p[2]) * ((const f16x2*)&lmH)[0];
        const f16x2 p3 = __builtin_elementwise_max(As[g] * vbp[3], A2s[g] * vb2p[3]) * ((const f16x2*)&lmH)[1];
        f16x8 a;
        ((f16x2*)&a)[0] = p0;
        ((f16x2*)&a)[1] = p1;
        ((f16x2*)&a)[2] = p2;
        ((f16x2*)&a)[3] = p3;
        ag[g] = a;
        if (w0) {
          den_s[g] = __builtin_amdgcn_fdot2(p0, ones2, den_s[g], false);
          den_s[g] = __builtin_amdgcn_fdot2(p1, ones2, den_s[g], false);
          den_s[g] = __builtin_amdgcn_fdot2(p2, ones2, den_s[g], false);
          den_s[g] = __builtin_amdgcn_fdot2(p3, ones2, den_s[g], false);
        }
      }
#pragma unroll
      for (int g = 0; g < 4; ++g) {
        acc[g][0] = __builtin_amdgcn_mfma_f32_16x16x32_f16(ag[g], cb0, acc[g][0], 0, 0, 0);
        acc[g][1] = __builtin_amdgcn_mfma_f32_16x16x32_f16(ag[g], cb1, acc[g][1], 0, 0, 0);
      }
      cb0 = nb0; cb1 = nb1; cvb = nvb; cvb2 = nvb2;
    }
  }
  // den: wave 0 only (wave-invariant); reduce over kg, lane col writes row.
  if (w0) {
#pragma unroll
    for (int g = 0; g < 4; ++g) {
      float d = den_s[g];
      d += __shfl_xor(d, 16, 64);
      d += __shfl_xor(d, 32, 64);
      if (kg == 0) {
        den_ws[(size_t)(s * 8 + h) * 4096 + i0 + g * 16 + col] = d;
      }
    }
  }
  // num partials: D frag row = g*16 + kg*4 + r, col o = w*32 + t*16 + col
  f16_t* np = num_ws + ((size_t)(s * 8 + h) * 4096 + i0) * 128;
#pragma unroll
  for (int g = 0; g < 4; ++g) {
#pragma unroll
    for (int t = 0; t < 2; ++t) {
#pragma unroll
      for (int r = 0; r < 4; ++r) {
        np[(g * 16 + kg * 4 + r) * 128 + w * 32 + t * 16 + col] = (f16_t)acc[g][t][r];
      }
    }
  }
}

// ---- K3: merge slices + normalize -> out[n][h*128+o] fp32 ----
__global__ __launch_bounds__(256) void k_merge(const f16_t* __restrict__ num_ws,
                                               const float* __restrict__ den_ws,
                                               float* __restrict__ out, int nslice) {
  const int g4 = (blockIdx.x * 256 + threadIdx.x) * 4;
  const int o = g4 & 127, h = (g4 >> 7) & 7, n = g4 >> 10;
  f32x4 sum = {};
  float d = 0.f;
  for (int sl = 0; sl < nslice; ++sl) {
    const f16x4 v = *(const f16x4*)(num_ws + ((size_t)((sl * 8 + h) * 4096) + n) * 128 + o);
#pragma unroll
    for (int i = 0; i < 4; ++i) sum[i] += (float)v[i];
    d += den_ws[(size_t)(sl * 8 + h) * 4096 + n];
  }
  const float inv = __builtin_amdgcn_rcpf(d);
  f32x4 r;
#pragma unroll
  for (int i = 0; i < 4; ++i) r[i] = sum[i] * inv;
  *(f32x4*)(out + g4) = r;
}

extern "C" void kernel_launch(void* const* d_in, const int* in_sizes, int n_in,
                              void* d_out, int out_size, void* d_ws, size_t ws_size,
                              hipStream_t stream) {
  const float* x = (const float*)d_in[0];
  const int* adj = (const int*)d_in[1];
  const float* W = (const float*)d_in[2];
  const float* a_src = (const float*)d_in[3];
  const float* a_dst = (const float*)d_in[4];
  float* out = (float*)d_out;
  char* ws = (char*)d_ws;
  // workspace layout (bytes):
  //   WhB   swizzled f16          : 0        .. 8388608
  //   xh    [4096][512] f16       : 8388608  .. 12582912
  //   WT    [8][128][512] f16     : 12582912 .. 13631488
  //   mask  [4096][512] u8        : 13631488 .. 15728640
  //   EA/EA2/EB/EB2 [8][4096] f16 : 15728640 .. 15990784 (4 x 64KB)
  //   den_ws [4][8][4096] f32     : 15990784 .. 16515072
  //   num_ws [4][8][4096][128] f16: 16515072 .. 50069504
  const size_t FIXED = 15990784;
  f16_t* WhB = (f16_t*)(ws);
  f16_t* xh = (f16_t*)(ws + 8388608);
  f16_t* WT = (f16_t*)(ws + 12582912);
  unsigned char* mask8 = (unsigned char*)(ws + 13631488);
  f16_t* EA = (f16_t*)(ws + 15728640);
  f16_t* EA2 = (f16_t*)(ws + 15794176);
  f16_t* EB = (f16_t*)(ws + 15859712);
  f16_t* EB2 = (f16_t*)(ws + 15925248);
  float* den_ws = (float*)(ws + FIXED);
  f16_t* num_ws = (f16_t*)(ws + FIXED + 524288);

  k_pack_adj<<<8192, 256, 0, stream>>>(adj, mask8);
  k_cvt_x<<<1024, 256, 0, stream>>>(x, xh);
  k_cvt_w<<<2048, 256, 0, stream>>>(W, WT);
  k_gemm_wh<<<dim3(64, 8), 256, 0, stream>>>(xh, WT, a_src, a_dst, WhB, EA, EA2, EB, EB2);
  k_pv<<<2048, 256, 0, stream>>>(WhB, EA, EA2, EB, EB2, mask8, num_ws, den_ws);
  k_merge<<<4096, 256, 0, stream>>>(num_ws, den_ws, out, 4);
}

// Round 11
// 115.130 us; speedup vs baseline: 1.2914x; 1.2914x over previous
//
#include <hip/hip_runtime.h>

#define LOG2E 1.44269504088896340736f

typedef _Float16 f16_t;
typedef f16_t f16x2 __attribute__((ext_vector_type(2)));
typedef f16_t f16x4 __attribute__((ext_vector_type(4)));
typedef f16_t f16x8 __attribute__((ext_vector_type(8)));
typedef float f32x4 __attribute__((ext_vector_type(4)));

// Problem constants: N=4096 nodes, F_in=512, F_out=128, H=8 heads.

// ---- K0a: pack adjacency (int32 0/1, 64MB) into bitmask (2MB) ----
__global__ __launch_bounds__(256) void k_pack_adj(const int* __restrict__ adj,
                                                  unsigned char* __restrict__ mask8) {
  const int t = blockIdx.x * 256 + threadIdx.x;  // 2M threads
  const int4 a = ((const int4*)adj)[t * 2];
  const int4 b = ((const int4*)adj)[t * 2 + 1];
  unsigned v = (a.x > 0) | ((a.y > 0) << 1) | ((a.z > 0) << 2) | ((a.w > 0) << 3) |
               ((b.x > 0) << 4) | ((b.y > 0) << 5) | ((b.z > 0) << 6) | ((b.w > 0) << 7);
  mask8[t] = (unsigned char)v;
}

// ---- K0b: x fp32 -> fp16 ----
__global__ __launch_bounds__(256) void k_cvt_x(const float* __restrict__ x,
                                               f16_t* __restrict__ xh) {
  const int t = blockIdx.x * 256 + threadIdx.x;
  const f32x4 a = ((const f32x4*)x)[t * 2];
  const f32x4 b = ((const f32x4*)x)[t * 2 + 1];
  f16x8 o;
#pragma unroll
  for (int i = 0; i < 4; ++i) { o[i] = (f16_t)a[i]; o[i + 4] = (f16_t)b[i]; }
  ((f16x8*)xh)[t] = o;
}

// ---- K0c: W [h][k][o] fp32 -> WT [h][o][k] fp16 ----
__global__ __launch_bounds__(256) void k_cvt_w(const float* __restrict__ W,
                                               f16_t* __restrict__ WT) {
  const int t = blockIdx.x * 256 + threadIdx.x;  // 524288
  const int k = t & 511, o = (t >> 9) & 127, h = t >> 16;
  WT[t] = (f16_t)W[((h << 9) + k) * 128 + o];
}

// ---- K1: Wh = x@W per head (fp16 MFMA). Store WhB pre-swizzled in PV
// B-fragment order; epilogue computes piecewise-exp tables
// EA=2^(fs*L), EA2=2^(0.2*fs*L), EB=2^(fd*L), EB2=2^(0.2*fd*L) as fp16.
__global__ __launch_bounds__(256) void k_gemm_wh(const f16_t* __restrict__ xh,
                                                 const f16_t* __restrict__ WT,
                                                 const float* __restrict__ a_src,
                                                 const float* __restrict__ a_dst,
                                                 f16_t* __restrict__ WhB,
                                                 f16_t* __restrict__ EA,
                                                 f16_t* __restrict__ EA2,
                                                 f16_t* __restrict__ EB,
                                                 f16_t* __restrict__ EB2) {
  const int h = blockIdx.y;
  const int n0 = blockIdx.x * 64;
  const int lane = threadIdx.x & 63;
  const int w = threadIdx.x >> 6;
  const int col = lane & 15;
  const int kg = lane >> 4;
  const f16_t* xrow = xh + (size_t)(n0 + w * 16 + col) * 512 + kg * 8;
  const f16_t* wb = WT + ((size_t)h << 16) + (size_t)col * 512 + kg * 8;
  f32x4 acc[8] = {};
  for (int kk = 0; kk < 512; kk += 32) {
    const f16x8 a = *(const f16x8*)(xrow + kk);
#pragma unroll
    for (int ot = 0; ot < 8; ++ot) {
      const f16x8 b = *(const f16x8*)(wb + ot * (16 * 512) + kk);
      acc[ot] = __builtin_amdgcn_mfma_f32_16x16x32_f16(a, b, acc[ot], 0, 0, 0);
    }
  }
  float ps[4] = {0.f, 0.f, 0.f, 0.f}, pd[4] = {0.f, 0.f, 0.f, 0.f};
#pragma unroll
  for (int ot = 0; ot < 8; ++ot) {
    const float as = a_src[h * 128 + ot * 16 + col];
    const float ad = a_dst[h * 128 + ot * 16 + col];
#pragma unroll
    for (int r = 0; r < 4; ++r) { ps[r] += acc[ot][r] * as; pd[r] += acc[ot][r] * ad; }
  }
#pragma unroll
  for (int m = 1; m < 16; m <<= 1) {
#pragma unroll
    for (int r = 0; r < 4; ++r) {
      ps[r] += __shfl_xor(ps[r], m, 64);
      pd[r] += __shfl_xor(pd[r], m, 64);
    }
  }
  const int nb = n0 + w * 16 + kg * 4;  // node index of acc[.][0]
  if (col == 0) {
#pragma unroll
    for (int r = 0; r < 4; ++r) {
      const float fs = ps[r] * LOG2E;
      const float fd = pd[r] * LOG2E;
      const int idx = h * 4096 + nb + r;
      EA[idx] = (f16_t)__builtin_amdgcn_exp2f(fs);
      EA2[idx] = (f16_t)__builtin_amdgcn_exp2f(0.2f * fs);
      EB[idx] = (f16_t)__builtin_amdgcn_exp2f(fd);
      EB2[idx] = (f16_t)__builtin_amdgcn_exp2f(0.2f * fd);
    }
  }
  // swizzled store: (h,o,j) -> WhB[((h*128+j/32)*8+o/16)*512 + ((j>>3)&3)*128 + (o&15)*8 + (j&7)]
  const int jb = nb >> 5;
  const int kgt = (nb >> 3) & 3;
  const int e0 = nb & 4;
  const size_t base = ((size_t)(h * 128 + jb) * 8) * 512 + kgt * 128 + col * 8 + e0;
#pragma unroll
  for (int ot = 0; ot < 8; ++ot) {
    f16x4 v;
#pragma unroll
    for (int r = 0; r < 4; ++r) v[r] = (f16_t)acc[ot][r];
    *(f16x4*)(WhB + base + ot * 512) = v;
  }
}

// ---- K2: masked softmax-numerator + PV partials ----
// Design F: wave w GENERATES the P-fragment for row-group w only (1x VALU,
// was 4x redundant), exchanges fragments via double-buffered LDS (1 barrier
// per iter; write(it+1) hits the opposite buffer of read(it), waves <=1
// barrier apart -> race-free), then each wave MFMAs all 4 fragments against
// its own o-quarter B-frags (direct from L2, 1-deep register prefetch).
// den is per-wave-exclusive (own rows). grid = 64 i-tiles x 8 heads x S=4
// j-slices = 2048 blocks; mask tile in LDS (pitch 144); nibble LUTs.
__global__ __launch_bounds__(256, 4) void k_pv(const f16_t* __restrict__ WhB,
                                               const f16_t* __restrict__ EA,
                                               const f16_t* __restrict__ EA2,
                                               const f16_t* __restrict__ EB,
                                               const f16_t* __restrict__ EB2,
                                               const unsigned char* __restrict__ mask,
                                               f16_t* __restrict__ num_ws,
                                               float* __restrict__ den_ws) {
  __shared__ __align__(16) unsigned char lds_mask[64 * 144];
  __shared__ __align__(16) unsigned short lut4[16][4];
  __shared__ __align__(16) f16_t lds_P[2][4][512];  // dbuf x 4 frags x 1KB
  const int bx = blockIdx.x;
  const int h = bx & 7;                  // head -> XCD round-robin
  const int i0 = ((bx >> 3) & 63) * 64;  // 64-row i-tile
  const int s = bx >> 9;                 // j-slice (0..3)
  const int jbeg = s * 1024;
  // stage mask tile: 64 rows x 128B, one-time coalesced copy (4 thr/row x 32B)
  {
    const int t = threadIdx.x;
    if (t < 16) {
#pragma unroll
      for (int e = 0; e < 4; ++e) lut4[t][e] = ((t >> e) & 1) ? 0x3C00 : 0;
    }
    const int row = t >> 2, ch = (t & 3) * 32;
    const uint4* src = (const uint4*)(mask + (size_t)(i0 + row) * 512 + (jbeg >> 3) + ch);
    uint4* dst = (uint4*)(lds_mask + row * 144 + ch);
    dst[0] = src[0];
    dst[1] = src[1];
  }
  __syncthreads();
  const int lane = threadIdx.x & 63;
  const int w = threadIdx.x >> 6;        // row-group owner (P-gen) AND o-quarter (MFMA)
  const int col = lane & 15, kg = lane >> 4;
  const int sh = kg * 8;
  f16x2 As, A2s;
  {
    const f16_t a = EA[h * 4096 + i0 + w * 16 + col];
    const f16_t a2 = EA2[h * 4096 + i0 + w * 16 + col];
    As = (f16x2){a, a};
    A2s = (f16x2){a2, a2};
  }
  const f16x2 ones2 = {(f16_t)1.0f, (f16_t)1.0f};
  const unsigned char* mrow = lds_mask + (w * 16 + col) * 144;
  const f16_t* EBp = EB + h * 4096 + jbeg + kg * 8;
  const f16_t* EB2p = EB2 + h * 4096 + jbeg + kg * 8;
  const f16_t* whB = WhB + ((size_t)h << 19) + (size_t)(jbeg >> 5) * 4096 + (2 * w) * 512 + lane * 8;
  f32x4 acc[4][2] = {};
  float den_s = 0.f;
  // prefetch iter 0
  f16x8 cb0 = *(const f16x8*)(whB);
  f16x8 cb1 = *(const f16x8*)(whB + 512);
  f16x8 cvb = *(const f16x8*)(EBp);
  f16x8 cvb2 = *(const f16x8*)(EB2p);
  for (int it4 = 0; it4 < 8; ++it4) {
    const uint4 md = *(const uint4*)(mrow + it4 * 16);
#pragma unroll
    for (int q = 0; q < 4; ++q) {
      const int it = it4 * 4 + q;
      const int itn = (it + 1) & 31;
      // issue next-iter prefetch early (hides L2 latency under P-gen+barrier)
      const f16_t* wpn = whB + (size_t)itn * 4096;
      const f16x8 nb0 = *(const f16x8*)(wpn);
      const f16x8 nb1 = *(const f16x8*)(wpn + 512);
      const f16x8 nvb = *(const f16x8*)(EBp + itn * 32);
      const f16x8 nvb2 = *(const f16x8*)(EB2p + itn * 32);
      // P-gen for OWN row-group only
      const unsigned mw = (q == 0) ? md.x : (q == 1) ? md.y : (q == 2) ? md.z : md.w;
      const unsigned bb = (mw >> sh) & 255u;
      const f16x4 lmL = *(const f16x4*)(&lut4[bb & 15u][0]);
      const f16x4 lmH = *(const f16x4*)(&lut4[bb >> 4][0]);
      const f16x2* vbp = (const f16x2*)&cvb;
      const f16x2* vb2p = (const f16x2*)&cvb2;
      f16x8 a;
      ((f16x2*)&a)[0] = __builtin_elementwise_max(As * vbp[0], A2s * vb2p[0]) * ((const f16x2*)&lmL)[0];
      ((f16x2*)&a)[1] = __builtin_elementwise_max(As * vbp[1], A2s * vb2p[1]) * ((const f16x2*)&lmL)[1];
      ((f16x2*)&a)[2] = __builtin_elementwise_max(As * vbp[2], A2s * vb2p[2]) * ((const f16x2*)&lmH)[0];
      ((f16x2*)&a)[3] = __builtin_elementwise_max(As * vbp[3], A2s * vb2p[3]) * ((const f16x2*)&lmH)[1];
      den_s = __builtin_amdgcn_fdot2(((const f16x2*)&a)[0], ones2, den_s, false);
      den_s = __builtin_amdgcn_fdot2(((const f16x2*)&a)[1], ones2, den_s, false);
      den_s = __builtin_amdgcn_fdot2(((const f16x2*)&a)[2], ones2, den_s, false);
      den_s = __builtin_amdgcn_fdot2(((const f16x2*)&a)[3], ones2, den_s, false);
      // exchange P fragments via LDS (double-buffered)
      *(f16x8*)(&lds_P[it & 1][w][lane * 8]) = a;
      __syncthreads();
      const f16x8 ag0 = *(const f16x8*)(&lds_P[it & 1][0][lane * 8]);
      const f16x8 ag1 = *(const f16x8*)(&lds_P[it & 1][1][lane * 8]);
      const f16x8 ag2 = *(const f16x8*)(&lds_P[it & 1][2][lane * 8]);
      const f16x8 ag3 = *(const f16x8*)(&lds_P[it & 1][3][lane * 8]);
      acc[0][0] = __builtin_amdgcn_mfma_f32_16x16x32_f16(ag0, cb0, acc[0][0], 0, 0, 0);
      acc[0][1] = __builtin_amdgcn_mfma_f32_16x16x32_f16(ag0, cb1, acc[0][1], 0, 0, 0);
      acc[1][0] = __builtin_amdgcn_mfma_f32_16x16x32_f16(ag1, cb0, acc[1][0], 0, 0, 0);
      acc[1][1] = __builtin_amdgcn_mfma_f32_16x16x32_f16(ag1, cb1, acc[1][1], 0, 0, 0);
      acc[2][0] = __builtin_amdgcn_mfma_f32_16x16x32_f16(ag2, cb0, acc[2][0], 0, 0, 0);
      acc[2][1] = __builtin_amdgcn_mfma_f32_16x16x32_f16(ag2, cb1, acc[2][1], 0, 0, 0);
      acc[3][0] = __builtin_amdgcn_mfma_f32_16x16x32_f16(ag3, cb0, acc[3][0], 0, 0, 0);
      acc[3][1] = __builtin_amdgcn_mfma_f32_16x16x32_f16(ag3, cb1, acc[3][1], 0, 0, 0);
      cb0 = nb0; cb1 = nb1; cvb = nvb; cvb2 = nvb2;
    }
  }
  // den: wave-exclusive rows (w*16 + col); reduce over kg k-slices.
  den_s += __shfl_xor(den_s, 16, 64);
  den_s += __shfl_xor(den_s, 32, 64);
  if (kg == 0) {
    den_ws[(size_t)(s * 8 + h) * 4096 + i0 + w * 16 + col] = den_s;
  }
  // num partials: D frag row = g*16 + kg*4 + r, col o = w*32 + t*16 + col
  f16_t* np = num_ws + ((size_t)(s * 8 + h) * 4096 + i0) * 128;
#pragma unroll
  for (int g = 0; g < 4; ++g) {
#pragma unroll
    for (int t = 0; t < 2; ++t) {
#pragma unroll
      for (int r = 0; r < 4; ++r) {
        np[(g * 16 + kg * 4 + r) * 128 + w * 32 + t * 16 + col] = (f16_t)acc[g][t][r];
      }
    }
  }
}

// ---- K3: merge slices + normalize -> out[n][h*128+o] fp32 ----
__global__ __launch_bounds__(256) void k_merge(const f16_t* __restrict__ num_ws,
                                               const float* __restrict__ den_ws,
                                               float* __restrict__ out, int nslice) {
  const int g4 = (blockIdx.x * 256 + threadIdx.x) * 4;
  const int o = g4 & 127, h = (g4 >> 7) & 7, n = g4 >> 10;
  f32x4 sum = {};
  float d = 0.f;
  for (int sl = 0; sl < nslice; ++sl) {
    const f16x4 v = *(const f16x4*)(num_ws + ((size_t)((sl * 8 + h) * 4096) + n) * 128 + o);
#pragma unroll
    for (int i = 0; i < 4; ++i) sum[i] += (float)v[i];
    d += den_ws[(size_t)(sl * 8 + h) * 4096 + n];
  }
  const float inv = __builtin_amdgcn_rcpf(d);
  f32x4 r;
#pragma unroll
  for (int i = 0; i < 4; ++i) r[i] = sum[i] * inv;
  *(f32x4*)(out + g4) = r;
}

extern "C" void kernel_launch(void* const* d_in, const int* in_sizes, int n_in,
                              void* d_out, int out_size, void* d_ws, size_t ws_size,
                              hipStream_t stream) {
  const float* x = (const float*)d_in[0];
  const int* adj = (const int*)d_in[1];
  const float* W = (const float*)d_in[2];
  const float* a_src = (const float*)d_in[3];
  const float* a_dst = (const float*)d_in[4];
  float* out = (float*)d_out;
  char* ws = (char*)d_ws;
  // workspace layout (bytes):
  //   WhB   swizzled f16          : 0        .. 8388608
  //   xh    [4096][512] f16       : 8388608  .. 12582912
  //   WT    [8][128][512] f16     : 12582912 .. 13631488
  //   mask  [4096][512] u8        : 13631488 .. 15728640
  //   EA/EA2/EB/EB2 [8][4096] f16 : 15728640 .. 15990784 (4 x 64KB)
  //   den_ws [4][8][4096] f32     : 15990784 .. 16515072
  //   num_ws [4][8][4096][128] f16: 16515072 .. 50069504
  const size_t FIXED = 15990784;
  f16_t* WhB = (f16_t*)(ws);
  f16_t* xh = (f16_t*)(ws + 8388608);
  f16_t* WT = (f16_t*)(ws + 12582912);
  unsigned char* mask8 = (unsigned char*)(ws + 13631488);
  f16_t* EA = (f16_t*)(ws + 15728640);
  f16_t* EA2 = (f16_t*)(ws + 15794176);
  f16_t* EB = (f16_t*)(ws + 15859712);
  f16_t* EB2 = (f16_t*)(ws + 15925248);
  float* den_ws = (float*)(ws + FIXED);
  f16_t* num_ws = (f16_t*)(ws + FIXED + 524288);

  k_pack_adj<<<8192, 256, 0, stream>>>(adj, mask8);
  k_cvt_x<<<1024, 256, 0, stream>>>(x, xh);
  k_cvt_w<<<2048, 256, 0, stream>>>(W, WT);
  k_gemm_wh<<<dim3(64, 8), 256, 0, stream>>>(xh, WT, a_src, a_dst, WhB, EA, EA2, EB, EB2);
  k_pv<<<2048, 256, 0, stream>>>(WhB, EA, EA2, EB, EB2, mask8, num_ws, den_ws);
  k_merge<<<4096, 256, 0, stream>>>(num_ws, den_ws, out, 4);
}